// Round 2
// baseline (52021.295 us; speedup 1.0000x reference)
//
#include <hip/hip_runtime.h>
#include <math.h>

// Problem dims
#define NWG 256
#define NTHR 512
static constexpr int S = 512, B = 64, I = 128, H = 512;

// ws layout (float units)
static constexpr size_t OFF_BUF0 = 0;
static constexpr size_t OFF_PCTX = (size_t)S * B * H;              // 16777216
static constexpr size_t OFF_PML  = OFF_PCTX + (size_t)B * 4 * H;
static constexpr size_t OFF_H2   = OFF_PML + (size_t)B * 4 * 2;
static constexpr size_t OFF_H3   = OFF_H2 + (size_t)2 * B * H;
static constexpr size_t OFF_BAR  = OFF_H3 + (size_t)2 * B * H;

// Grid-wide barrier: gen-counter, device(agent)-scope acq/rel.
__device__ __forceinline__ void gbar(unsigned* __restrict__ bar) {
  __syncthreads();
  if (threadIdx.x == 0) {
    unsigned g = __hip_atomic_load(bar + 1, __ATOMIC_RELAXED, __HIP_MEMORY_SCOPE_AGENT);
    unsigned a = __hip_atomic_fetch_add(bar, 1u, __ATOMIC_ACQ_REL, __HIP_MEMORY_SCOPE_AGENT);
    if (a == (unsigned)(NWG - 1)) {
      __hip_atomic_store(bar, 0u, __ATOMIC_RELAXED, __HIP_MEMORY_SCOPE_AGENT);
      __hip_atomic_store(bar + 1, g + 1u, __ATOMIC_RELEASE, __HIP_MEMORY_SCOPE_AGENT);
    } else {
      while (__hip_atomic_load(bar + 1, __ATOMIC_ACQUIRE, __HIP_MEMORY_SCOPE_AGENT) == g) {
        __builtin_amdgcn_s_sleep(1);
      }
    }
  }
  __syncthreads();
}

__global__ __launch_bounds__(NTHR, 2) void attn_fused(
    const float* __restrict__ inputs,
    const float* __restrict__ Wih_pre, const float* __restrict__ Whh_pre,
    const float* __restrict__ bih_pre, const float* __restrict__ bhh_pre,
    const float* __restrict__ Wih_post, const float* __restrict__ Whh_post,
    const float* __restrict__ bih_post, const float* __restrict__ bhh_post,
    const float* __restrict__ Wfc, const float* __restrict__ bfc,
    float* __restrict__ out, float* __restrict__ ws)
{
  float* buf0 = ws + OFF_BUF0;
  float* pctx = ws + OFF_PCTX;
  float* pml  = ws + OFF_PML;
  float* h2   = ws + OFF_H2;
  float* h3   = ws + OFF_H3;
  unsigned* bar = (unsigned*)(ws + OFF_BAR);

  const int wg   = blockIdx.x;
  const int tid  = threadIdx.x;
  const int lane = tid & 63;
  const int wv   = tid >> 6;   // wave id 0..7

  // [0,8192): P1 tile / 3a ctx merge (uses [0,4096)) / 3c ctx2+hst staging
  // [8192,8208): 3a per-wave (m,l)
  __shared__ float smem[8208];

  // ================= P1: x_proj = inputs @ W_ih_pre^T + (b_ih+b_hh) ==========
  {
    const int h = tid;  // 512 threads = 512 h columns
    float4 Wr[32];      // full W row (128 fp32) stationary in regs
    const float4* wrow = (const float4*)(Wih_pre + (size_t)h * I);
    #pragma unroll
    for (int c = 0; c < 32; ++c) Wr[c] = wrow[c];
    const float bias = bih_pre[h] + bhh_pre[h];
    const int r0 = wg * 128;  // 128 flattened (s*B+b) rows per WG
    for (int t2 = 0; t2 < 2; ++t2) {
      __syncthreads();
      const float4* src = (const float4*)(inputs + (size_t)(r0 + t2 * 64) * I);
      for (int idx = tid; idx < 64 * I / 4; idx += NTHR)
        ((float4*)smem)[idx] = src[idx];
      __syncthreads();
      for (int r = 0; r < 64; ++r) {
        const float4* arow = (const float4*)(smem + r * I);
        float acc0 = 0.f, acc1 = 0.f;
        #pragma unroll
        for (int c = 0; c < 32; c += 2) {
          float4 a0 = arow[c], a1 = arow[c + 1];
          acc0 += a0.x * Wr[c].x + a0.y * Wr[c].y + a0.z * Wr[c].z + a0.w * Wr[c].w;
          acc1 += a1.x * Wr[c+1].x + a1.y * Wr[c+1].y + a1.z * Wr[c+1].z + a1.w * Wr[c+1].w;
        }
        buf0[(size_t)(r0 + t2 * 64 + r) * H + h] = acc0 + acc1 + bias;
      }
    }
  }
  gbar(bar);

  // ================= P2: pre-RNN, 512 sequential steps ======================
  // WG = (bg 0..7) x (jg 0..31); wave handles j-pair {j0, j0+1} for 8 batches.
  {
    const int bg = wg >> 5;
    const int jg = wg & 31;
    const int j0 = jg * 16 + wv * 2;
    float w0[8], w1[8];  // W_hh rows stationary
    #pragma unroll
    for (int ki = 0; ki < 8; ++ki) {
      w0[ki] = Whh_pre[(size_t)j0 * H + lane + 64 * ki];
      w1[ki] = Whh_pre[(size_t)(j0 + 1) * H + lane + 64 * ki];
    }
    for (int t = 0; t < S; ++t) {
      const float* hin = h2 + (size_t)(t & 1) * (B * H);
      float* hout      = h2 + (size_t)((t + 1) & 1) * (B * H);
      for (int bi = 0; bi < 8; ++bi) {
        const int b = bg * 8 + bi;
        const size_t xoff = ((size_t)t * B + b) * H + j0;
        float xp0 = buf0[xoff];        // includes both biases
        float xp1 = buf0[xoff + 1];
        float hk[8];
        #pragma unroll
        for (int ki = 0; ki < 8; ++ki) hk[ki] = hin[(size_t)b * H + lane + 64 * ki];
        float d0 = 0.f, d1 = 0.f;
        #pragma unroll
        for (int ki = 0; ki < 8; ++ki) { d0 += hk[ki] * w0[ki]; d1 += hk[ki] * w1[ki]; }
        #pragma unroll
        for (int off = 32; off > 0; off >>= 1) {
          d0 += __shfl_xor(d0, off);
          d1 += __shfl_xor(d1, off);
        }
        float h0n = tanhf(xp0 + d0);
        float h1n = tanhf(xp1 + d1);
        if (lane == 0) {
          hout[(size_t)b * H + j0]     = h0n;
          hout[(size_t)b * H + j0 + 1] = h1n;
          buf0[xoff]     = h0n;   // out_pre overwrites x_proj in place
          buf0[xoff + 1] = h1n;
        }
      }
      gbar(bar);
    }
  }

  // ================= P3: attention loop, 512 sequential steps ================
  const int b3    = wg >> 2;   // 3a: batch
  const int strip = wg & 3;    // 3a: s-strip (128 s each)
  const int bg    = wg >> 5;   // 3c: batch group (8 batches)
  const int jg    = wg & 31;   // 3c: j group (16 j)
  const int j0    = jg * 16 + wv * 2;

  // [W_ih_post | W_hh_post] rows stationary in regs for 3c
  float wc0[16], wc1[16];
  #pragma unroll
  for (int ki = 0; ki < 16; ++ki) {
    int k = lane + 64 * ki;
    wc0[ki] = (k < H) ? Wih_post[(size_t)j0 * H + k] : Whh_post[(size_t)j0 * H + (k - H)];
    wc1[ki] = (k < H) ? Wih_post[(size_t)(j0 + 1) * H + k] : Whh_post[(size_t)(j0 + 1) * H + (k - H)];
  }
  const float bp0 = bih_post[j0] + bhh_post[j0];
  const float bp1 = bih_post[j0 + 1] + bhh_post[j0 + 1];

  // ---- G = out_pre strip, register-resident for the whole attention loop ----
  // lane holds h-slice [lane*8, lane*8+8) for 16 s-rows: ga (first 4) gb (last 4)
  float4 ga[16], gb[16];
  {
    const int s0 = strip * 128 + wv * 16;
    #pragma unroll
    for (int i = 0; i < 16; ++i) {
      const float4* row = (const float4*)(buf0 + ((size_t)(s0 + i) * B + b3) * H + (size_t)lane * 8);
      ga[i] = row[0];
      gb[i] = row[1];
    }
  }

  for (int u = 0; u < H; ++u) {
    const float* hin = h3 + (size_t)(u & 1) * (B * H);
    float* hout      = h3 + (size_t)((u + 1) & 1) * (B * H);

    // ---- 3a: scores + softmax partials + ctx partial, all from registers ----
    {
      const float* hb = hin + (size_t)b3 * H + (size_t)lane * 8;
      float4 h0 = ((const float4*)hb)[0];
      float4 h1 = ((const float4*)hb)[1];
      float p[16];
      #pragma unroll
      for (int i = 0; i < 16; ++i)
        p[i] = ga[i].x * h0.x + ga[i].y * h0.y + ga[i].z * h0.z + ga[i].w * h0.w
             + gb[i].x * h1.x + gb[i].y * h1.y + gb[i].z * h1.z + gb[i].w * h1.w;
      #pragma unroll
      for (int off = 32; off > 0; off >>= 1) {
        #pragma unroll
        for (int i = 0; i < 16; ++i) p[i] += __shfl_xor(p[i], off);
      }
      // all lanes now hold all 16 full scores
      float m = p[0];
      #pragma unroll
      for (int i = 1; i < 16; ++i) m = fmaxf(m, p[i]);
      float l = 0.f;
      float4 c0{0.f,0.f,0.f,0.f}, c1{0.f,0.f,0.f,0.f};
      #pragma unroll
      for (int i = 0; i < 16; ++i) {
        float e = __expf(p[i] - m);
        l += e;
        c0.x += e * ga[i].x;  c0.y += e * ga[i].y;  c0.z += e * ga[i].z;  c0.w += e * ga[i].w;
        c1.x += e * gb[i].x;  c1.y += e * gb[i].y;  c1.z += e * gb[i].z;  c1.w += e * gb[i].w;
      }
      // merge 8 waves in LDS
      float* ctx_lds = smem;          // [8][512]
      float* ml_lds  = smem + 8192;   // [8][2]
      *(float4*)(ctx_lds + wv * 512 + lane * 8)     = c0;
      *(float4*)(ctx_lds + wv * 512 + lane * 8 + 4) = c1;
      if (lane == 0) { ml_lds[wv * 2] = m; ml_lds[wv * 2 + 1] = l; }
      __syncthreads();
      float mstar = ml_lds[0];
      #pragma unroll
      for (int w = 1; w < 8; ++w) mstar = fmaxf(mstar, ml_lds[w * 2]);
      float lsum = 0.f, csum = 0.f;
      #pragma unroll
      for (int w = 0; w < 8; ++w) {
        float sc = __expf(ml_lds[w * 2] - mstar);
        lsum += sc * ml_lds[w * 2 + 1];
        csum += sc * ctx_lds[w * 512 + tid];
      }
      pctx[((size_t)b3 * 4 + strip) * H + tid] = csum;
      if (tid == 0) {
        pml[((size_t)b3 * 4 + strip) * 2]     = mstar;
        pml[((size_t)b3 * 4 + strip) * 2 + 1] = lsum;
      }
    }
    gbar(bar);

    // ---- 3c: merge strip partials -> ctx; h-update GEMV with stationary W
    {
      float* ctx2 = smem;         // [8][512]
      float* hst  = smem + 4096;  // [8][512]
      for (int bi = 0; bi < 8; ++bi) {
        const int b = bg * 8 + bi;
        const float* ml = pml + (size_t)b * 8;
        float m0 = ml[0], l0 = ml[1], m1 = ml[2], l1 = ml[3];
        float m2 = ml[4], l2 = ml[5], m3 = ml[6], l3 = ml[7];
        float mb = fmaxf(fmaxf(m0, m1), fmaxf(m2, m3));
        float s0 = __expf(m0 - mb), s1 = __expf(m1 - mb);
        float s2 = __expf(m2 - mb), s3 = __expf(m3 - mb);
        float inv = 1.0f / (s0 * l0 + s1 * l1 + s2 * l2 + s3 * l3);
        const float* pc = pctx + (size_t)b * 4 * H;
        float c = (s0 * pc[0 * H + tid] + s1 * pc[1 * H + tid] +
                   s2 * pc[2 * H + tid] + s3 * pc[3 * H + tid]) * inv;
        ctx2[bi * H + tid] = c;
        hst[bi * H + tid]  = hin[(size_t)b * H + tid];
      }
      __syncthreads();
      for (int bi = 0; bi < 8; ++bi) {
        float d0 = 0.f, d1 = 0.f;
        #pragma unroll
        for (int ki = 0; ki < 16; ++ki) {
          int kk = lane + 64 * ki;
          float v = (ki < 8) ? ctx2[bi * H + kk] : hst[bi * H + (kk - H)];
          d0 += v * wc0[ki];
          d1 += v * wc1[ki];
        }
        #pragma unroll
        for (int off = 32; off > 0; off >>= 1) {
          d0 += __shfl_xor(d0, off);
          d1 += __shfl_xor(d1, off);
        }
        float h0n = tanhf(d0 + bp0);
        float h1n = tanhf(d1 + bp1);
        if (lane == 0) {
          const int b = bg * 8 + bi;
          hout[(size_t)b * H + j0]     = h0n;
          hout[(size_t)b * H + j0 + 1] = h1n;
        }
      }
    }
    gbar(bar);
  }

  // ================= final: out = h_post @ W_fc^T + b_fc =====================
  if (wg == 0) {
    const float* hf = h3;  // 512 steps -> final parity slot 0
    for (int i = 0; i < 8; ++i) {
      const int b = wv * 8 + i;
      float d = 0.f;
      #pragma unroll
      for (int ki = 0; ki < 8; ++ki) {
        int k = lane + 64 * ki;
        d += hf[(size_t)b * H + k] * Wfc[k];
      }
      #pragma unroll
      for (int off = 32; off > 0; off >>= 1) d += __shfl_xor(d, off);
      if (lane == 0) out[b] = d + bfc[0];
    }
  }
}

extern "C" void kernel_launch(void* const* d_in, const int* in_sizes, int n_in,
                              void* d_out, int out_size, void* d_ws, size_t ws_size,
                              hipStream_t stream) {
  (void)in_sizes; (void)n_in; (void)out_size; (void)ws_size;
  const float* inputs   = (const float*)d_in[0];
  const float* Wih_pre  = (const float*)d_in[1];
  const float* Whh_pre  = (const float*)d_in[2];
  const float* bih_pre  = (const float*)d_in[3];
  const float* bhh_pre  = (const float*)d_in[4];
  const float* Wih_post = (const float*)d_in[5];
  const float* Whh_post = (const float*)d_in[6];
  const float* bih_post = (const float*)d_in[7];
  const float* bhh_post = (const float*)d_in[8];
  const float* Wfc      = (const float*)d_in[9];
  const float* bfc      = (const float*)d_in[10];
  float* out = (float*)d_out;
  float* ws  = (float*)d_ws;

  // Zero h double-buffers + barrier state every launch (deterministic under
  // graph replay; ws is poisoned 0xAA once and never re-poisoned).
  size_t zoff = OFF_H2 * sizeof(float);
  size_t zlen = (OFF_BAR - OFF_H2) * sizeof(float) + 8;
  hipMemsetAsync((char*)d_ws + zoff, 0, zlen, stream);

  attn_fused<<<dim3(NWG), dim3(NTHR), 0, stream>>>(
      inputs, Wih_pre, Whh_pre, bih_pre, bhh_pre,
      Wih_post, Whh_post, bih_post, bhh_post, Wfc, bfc, out, ws);
}

// Round 3
// 23189.021 us; speedup vs baseline: 2.2434x; 2.2434x over previous
//
#include <hip/hip_runtime.h>
#include <math.h>

#define NWG 256
#define NTHR 512
static constexpr int S = 512, B = 64, I = 128, H = 512;

// ws layout (float units)
static constexpr size_t OFF_BUF0   = 0;                                // S*B*H (x_proj -> out_pre in place)
static constexpr size_t OFF_PCTX   = (size_t)S * B * H;                // 16777216, B*4*H
static constexpr size_t OFF_PML    = OFF_PCTX + (size_t)B * 4 * H;     // B*4*2
static constexpr size_t OFF_H3     = OFF_PML + (size_t)B * 4 * 2;      // 2*B*H (attention h ping-pong)
static constexpr size_t OFF_GFLAGS = OFF_H3 + (size_t)2 * B * H;       // 256 slots * 32 uint
static constexpr size_t OFF_BFLAGS = OFF_GFLAGS + (size_t)256 * 32;    // 64 batches * 4 slots * 32 uint
static constexpr size_t OFF_END    = OFF_BFLAGS + (size_t)B * 4 * 32;

// 4-WG (one batch) flag barrier: each member release-stores gen to its own
// 128B slot; 4 lanes poll the 4 slots. No RMW contention, XCD-local if
// dispatch round-robins (members b, b+64, b+128, b+192 are == b mod 8).
__device__ __forceinline__ void gbar4(unsigned* __restrict__ gf, int part, unsigned gen) {
  __syncthreads();
  if (threadIdx.x == 0)
    __hip_atomic_store(gf + (size_t)part * 32, gen, __ATOMIC_RELEASE, __HIP_MEMORY_SCOPE_AGENT);
  if (threadIdx.x < 4) {
    while (__hip_atomic_load(gf + (size_t)threadIdx.x * 32, __ATOMIC_ACQUIRE,
                             __HIP_MEMORY_SCOPE_AGENT) < gen) {}
  }
  __syncthreads();
}

__global__ __launch_bounds__(NTHR, 2) void attn_fused(
    const float* __restrict__ inputs,
    const float* __restrict__ Wih_pre, const float* __restrict__ Whh_pre,
    const float* __restrict__ bih_pre, const float* __restrict__ bhh_pre,
    const float* __restrict__ Wih_post, const float* __restrict__ Whh_post,
    const float* __restrict__ bih_post, const float* __restrict__ bhh_post,
    const float* __restrict__ Wfc, const float* __restrict__ bfc,
    float* __restrict__ out, float* __restrict__ ws)
{
  float* buf0 = ws + OFF_BUF0;
  float* pctx = ws + OFF_PCTX;
  float* pml  = ws + OFF_PML;
  float* h3   = ws + OFF_H3;
  unsigned* gflags = (unsigned*)(ws + OFF_GFLAGS);

  const int wg   = blockIdx.x;
  const int tid  = threadIdx.x;
  const int lane = tid & 63;
  const int wv   = tid >> 6;
  const int b    = wg & 63;    // batch owned by this WG (4 WGs per batch)
  const int part = wg >> 6;    // 0..3: j-part for GEMVs, s-strip for 3a

  unsigned* bflags = (unsigned*)(ws + OFF_BFLAGS) + (size_t)b * 4 * 32;
  unsigned gen = 0;

  __shared__ float smem[8208];  // P1 tile (8192) / 3a merge (4096+16) / staging (1024)

  // ================= P1: x_proj = inputs @ W_ih_pre^T + (b_ih+b_hh) ==========
  {
    const int h = tid;
    float4 Wr[32];
    const float4* wrow = (const float4*)(Wih_pre + (size_t)h * I);
    #pragma unroll
    for (int c = 0; c < 32; ++c) Wr[c] = wrow[c];
    const float bias = bih_pre[h] + bhh_pre[h];
    const int r0 = wg * 128;
    for (int t2 = 0; t2 < 2; ++t2) {
      __syncthreads();
      const float4* src = (const float4*)(inputs + (size_t)(r0 + t2 * 64) * I);
      for (int idx = tid; idx < 64 * I / 4; idx += NTHR)
        ((float4*)smem)[idx] = src[idx];
      __syncthreads();
      for (int r = 0; r < 64; ++r) {
        const float4* arow = (const float4*)(smem + r * I);
        float acc0 = 0.f, acc1 = 0.f;
        #pragma unroll
        for (int c = 0; c < 32; c += 2) {
          float4 a0 = arow[c], a1 = arow[c + 1];
          acc0 += a0.x * Wr[c].x + a0.y * Wr[c].y + a0.z * Wr[c].z + a0.w * Wr[c].w;
          acc1 += a1.x * Wr[c+1].x + a1.y * Wr[c+1].y + a1.z * Wr[c+1].z + a1.w * Wr[c+1].w;
        }
        buf0[(size_t)(r0 + t2 * 64 + r) * H + h] = acc0 + acc1 + bias;
      }
    }
  }
  // ---- one 256-WG flag barrier (parallel arrival, parallel poll) ----
  __syncthreads();
  if (tid == 0)
    __hip_atomic_store(gflags + (size_t)wg * 32, 1u, __ATOMIC_RELEASE, __HIP_MEMORY_SCOPE_AGENT);
  if (tid < 256) {
    while (__hip_atomic_load(gflags + (size_t)tid * 32, __ATOMIC_ACQUIRE,
                             __HIP_MEMORY_SCOPE_AGENT) < 1u) {}
  }
  __syncthreads();

  // ================= P2: pre-RNN, 512 steps, per-batch (4 WGs) ==============
  // thread: j = part*128 + (tid>>2), k-quad kq = tid&3, k-blocks interleaved
  {
    const int j  = part * 128 + (tid >> 2);
    const int kq = tid & 3;
    float4 wpre[32];
    const float4* wrow = (const float4*)(Whh_pre + (size_t)j * H);
    #pragma unroll
    for (int i = 0; i < 32; ++i) wpre[i] = wrow[4 * i + kq];

    float* hst  = smem;            // [512] current h for this batch
    float4* hst4 = (float4*)smem;
    hst[tid] = 0.f;
    __syncthreads();

    for (int t = 0; t < S; ++t) {
      float* brow = buf0 + ((size_t)t * B + b) * H;
      float xp = brow[j];  // x_proj incl. both biases
      float d = 0.f;
      #pragma unroll
      for (int i = 0; i < 32; ++i) {
        float4 hv = hst4[4 * i + kq];   // 4 distinct addrs, 16-way broadcast: conflict-free
        d += wpre[i].x * hv.x + wpre[i].y * hv.y + wpre[i].z * hv.z + wpre[i].w * hv.w;
      }
      d += __shfl_xor(d, 1);
      d += __shfl_xor(d, 2);
      float hnew = tanhf(xp + d);
      if (kq == 0) brow[j] = hnew;      // out_pre overwrites x_proj in place
      gbar4(bflags, part, ++gen);
      if (tid < 128) hst4[tid] = ((const float4*)brow)[tid];  // reload full h_t
      __syncthreads();
    }
  }

  // ---- G = out_pre strip (128 s-rows), register-resident ----
  // lane holds h-dims [lane*4,+4) (ga) and [256+lane*4,+4) (gb); wave = 16 rows
  float4 ga[16], gb[16];
  {
    const int s0 = part * 128 + wv * 16;
    #pragma unroll
    for (int i = 0; i < 16; ++i) {
      const float* row = buf0 + ((size_t)(s0 + i) * B + b) * H;
      ga[i] = *(const float4*)(row + lane * 4);
      gb[i] = *(const float4*)(row + 256 + lane * 4);
    }
  }

  // ---- 3c stationary weights: [W_ih_post | W_hh_post] ----
  const int j3 = part * 128 + (tid >> 2);
  const int kq = tid & 3;
  float4 wih[32], whh[32];
  {
    const float4* wr1 = (const float4*)(Wih_post + (size_t)j3 * H);
    const float4* wr2 = (const float4*)(Whh_post + (size_t)j3 * H);
    #pragma unroll
    for (int i = 0; i < 32; ++i) { wih[i] = wr1[4 * i + kq]; whh[i] = wr2[4 * i + kq]; }
  }
  const float bp3 = bih_post[j3] + bhh_post[j3];

  // ================= P3: attention loop, 512 steps, per-batch ================
  for (int u = 0; u < H; ++u) {
    const float* hin = h3 + (size_t)(u & 1) * (B * H) + (size_t)b * H;
    float* hout      = h3 + (size_t)((u + 1) & 1) * (B * H) + (size_t)b * H;

    // ---- 3a: scores + softmax partials + ctx partial (registers) ----
    {
      float4 h0v = *(const float4*)(hin + lane * 4);
      float4 h1v = *(const float4*)(hin + 256 + lane * 4);
      float p[16];
      #pragma unroll
      for (int i = 0; i < 16; ++i)
        p[i] = ga[i].x * h0v.x + ga[i].y * h0v.y + ga[i].z * h0v.z + ga[i].w * h0v.w
             + gb[i].x * h1v.x + gb[i].y * h1v.y + gb[i].z * h1v.z + gb[i].w * h1v.w;
      #pragma unroll
      for (int off = 32; off > 0; off >>= 1) {
        #pragma unroll
        for (int i = 0; i < 16; ++i) p[i] += __shfl_xor(p[i], off);
      }
      float m = p[0];
      #pragma unroll
      for (int i = 1; i < 16; ++i) m = fmaxf(m, p[i]);
      float l = 0.f;
      float4 c0{0.f,0.f,0.f,0.f}, c1{0.f,0.f,0.f,0.f};
      #pragma unroll
      for (int i = 0; i < 16; ++i) {
        float e = __expf(p[i] - m);
        l += e;
        c0.x += e * ga[i].x;  c0.y += e * ga[i].y;  c0.z += e * ga[i].z;  c0.w += e * ga[i].w;
        c1.x += e * gb[i].x;  c1.y += e * gb[i].y;  c1.z += e * gb[i].z;  c1.w += e * gb[i].w;
      }
      float* ctx_lds = smem;          // [8][512], identity h-dim layout
      float* ml_lds  = smem + 4096;   // [8][2]
      *(float4*)(ctx_lds + wv * 512 + lane * 4)       = c0;
      *(float4*)(ctx_lds + wv * 512 + 256 + lane * 4) = c1;
      if (lane == 0) { ml_lds[wv * 2] = m; ml_lds[wv * 2 + 1] = l; }
      __syncthreads();
      float mstar = ml_lds[0];
      #pragma unroll
      for (int w = 1; w < 8; ++w) mstar = fmaxf(mstar, ml_lds[w * 2]);
      float lsum = 0.f, csum = 0.f;
      #pragma unroll
      for (int w = 0; w < 8; ++w) {
        float sc = __expf(ml_lds[w * 2] - mstar);
        lsum += sc * ml_lds[w * 2 + 1];
        csum += sc * ctx_lds[w * 512 + tid];
      }
      pctx[((size_t)b * 4 + part) * H + tid] = csum;
      if (tid == 0) {
        pml[((size_t)b * 4 + part) * 2]     = mstar;
        pml[((size_t)b * 4 + part) * 2 + 1] = lsum;
      }
    }
    gbar4(bflags, part, ++gen);

    // ---- 3c: merge 4 strip partials -> ctx; h-update GEMV (stationary W) ----
    {
      float* ctx2 = smem;          // [512]
      float* hst  = smem + 512;    // [512]
      const float* ml8 = pml + (size_t)b * 8;
      float m0 = ml8[0], l0 = ml8[1], m1 = ml8[2], l1 = ml8[3];
      float m2 = ml8[4], l2 = ml8[5], m3 = ml8[6], l3 = ml8[7];
      float mb = fmaxf(fmaxf(m0, m1), fmaxf(m2, m3));
      float s0 = __expf(m0 - mb), s1 = __expf(m1 - mb);
      float s2 = __expf(m2 - mb), s3 = __expf(m3 - mb);
      float inv = 1.0f / (s0 * l0 + s1 * l1 + s2 * l2 + s3 * l3);
      const float* pc = pctx + (size_t)b * 4 * H;
      ctx2[tid] = (s0 * pc[tid] + s1 * pc[H + tid] +
                   s2 * pc[2 * H + tid] + s3 * pc[3 * H + tid]) * inv;
      hst[tid] = hin[tid];
      __syncthreads();
      const float4* ctx4 = (const float4*)ctx2;
      const float4* hh4  = (const float4*)hst;
      float acc = 0.f;
      #pragma unroll
      for (int i = 0; i < 32; ++i) {
        float4 cv = ctx4[4 * i + kq];
        float4 hv = hh4[4 * i + kq];
        acc += wih[i].x * cv.x + wih[i].y * cv.y + wih[i].z * cv.z + wih[i].w * cv.w
             + whh[i].x * hv.x + whh[i].y * hv.y + whh[i].z * hv.z + whh[i].w * hv.w;
      }
      acc += __shfl_xor(acc, 1);
      acc += __shfl_xor(acc, 2);
      if (kq == 0) hout[j3] = tanhf(acc + bp3);
    }
    gbar4(bflags, part, ++gen);
  }

  // ================= final: out = h_post @ W_fc^T + b_fc =====================
  if (part == 0) {
    const float* hf = h3 + (size_t)b * H;   // 512 steps -> parity slot 0
    float pv = hf[tid] * Wfc[tid];
    #pragma unroll
    for (int off = 32; off > 0; off >>= 1) pv += __shfl_xor(pv, off);
    __syncthreads();
    if (lane == 0) smem[wv] = pv;
    __syncthreads();
    if (tid == 0) {
      float s = 0.f;
      #pragma unroll
      for (int w = 0; w < 8; ++w) s += smem[w];
      out[b] = s + bfc[0];
    }
  }
}

extern "C" void kernel_launch(void* const* d_in, const int* in_sizes, int n_in,
                              void* d_out, int out_size, void* d_ws, size_t ws_size,
                              hipStream_t stream) {
  (void)in_sizes; (void)n_in; (void)out_size; (void)ws_size;
  const float* inputs   = (const float*)d_in[0];
  const float* Wih_pre  = (const float*)d_in[1];
  const float* Whh_pre  = (const float*)d_in[2];
  const float* bih_pre  = (const float*)d_in[3];
  const float* bhh_pre  = (const float*)d_in[4];
  const float* Wih_post = (const float*)d_in[5];
  const float* Whh_post = (const float*)d_in[6];
  const float* bih_post = (const float*)d_in[7];
  const float* bhh_post = (const float*)d_in[8];
  const float* Wfc      = (const float*)d_in[9];
  const float* bfc      = (const float*)d_in[10];
  float* out = (float*)d_out;
  float* ws  = (float*)d_ws;

  // Zero h3 ping-pong + all barrier flags (contiguous region), every launch.
  hipMemsetAsync((char*)d_ws + OFF_H3 * sizeof(float), 0,
                 (OFF_END - OFF_H3) * sizeof(float), stream);

  attn_fused<<<dim3(NWG), dim3(NTHR), 0, stream>>>(
      inputs, Wih_pre, Whh_pre, bih_pre, bhh_pre,
      Wih_post, Whh_post, bih_post, bhh_post, Wfc, bfc, out, ws);
}

// Round 4
// 16324.208 us; speedup vs baseline: 3.1868x; 1.4205x over previous
//
#include <hip/hip_runtime.h>
#include <math.h>

#define NWG 256
#define NTHR 512
static constexpr int S = 512, B = 64, I = 128, H = 512;

// ws layout (float units)
static constexpr size_t OFF_BUF0   = 0;                                // S*B*H (x_proj -> out_pre in place)
static constexpr size_t OFF_PCTX   = (size_t)S * B * H;                // B*4*H
static constexpr size_t OFF_PML    = OFF_PCTX + (size_t)B * 4 * H;     // B*4*2
static constexpr size_t OFF_H3     = OFF_PML + (size_t)B * 4 * 2;      // 2*B*H (attention h ping-pong)
static constexpr size_t OFF_GFLAGS = OFF_H3 + (size_t)2 * B * H;       // 256 slots * 32 uint
static constexpr size_t OFF_BFLAGS = OFF_GFLAGS + (size_t)256 * 32;    // 64 batches * 4 slots * 32 uint
static constexpr size_t OFF_END    = OFF_BFLAGS + (size_t)B * 4 * 32;

// ---- relaxed agent-scope (sc1, L2-bypassing, coherent) scalar ops ----------
// Relaxed atomics emit NO cache-maintenance (no buffer_wbl2/buffer_inv); the
// access itself is performed at the device coherence point.
__device__ __forceinline__ float cload(const float* p) {
  union { float f; unsigned u; } c;
  c.u = __hip_atomic_load((const unsigned*)p, __ATOMIC_RELAXED, __HIP_MEMORY_SCOPE_AGENT);
  return c.f;
}
__device__ __forceinline__ void cstore(float* p, float v) {
  union { float f; unsigned u; } c; c.f = v;
  __hip_atomic_store((unsigned*)p, c.u, __ATOMIC_RELAXED, __HIP_MEMORY_SCOPE_AGENT);
}
__device__ __forceinline__ float2 cload2(const float* p) {  // 8B-aligned
  union { unsigned long long u; float2 f; } c;
  c.u = __hip_atomic_load((const unsigned long long*)p, __ATOMIC_RELAXED, __HIP_MEMORY_SCOPE_AGENT);
  return c.f;
}

// 4-WG (one batch) flag barrier, RELAXED only. Ordering: __syncthreads()
// drains vmcnt(0) per wave (all prior sc1 data stores acked at coherence
// point) before the flag store; consumers then read data with sc1 loads.
__device__ __forceinline__ void bar4(unsigned* __restrict__ gf, int part, unsigned gen) {
  __syncthreads();
  if (threadIdx.x == 0)
    __hip_atomic_store(gf + (size_t)part * 32, gen, __ATOMIC_RELAXED, __HIP_MEMORY_SCOPE_AGENT);
  if (threadIdx.x < 4) {
    while (__hip_atomic_load(gf + (size_t)threadIdx.x * 32, __ATOMIC_RELAXED,
                             __HIP_MEMORY_SCOPE_AGENT) < gen) {}
  }
  __syncthreads();
  asm volatile("" ::: "memory");
}

__global__ __launch_bounds__(NTHR, 2) void attn_fused(
    const float* __restrict__ inputs,
    const float* __restrict__ Wih_pre, const float* __restrict__ Whh_pre,
    const float* __restrict__ bih_pre, const float* __restrict__ bhh_pre,
    const float* __restrict__ Wih_post, const float* __restrict__ Whh_post,
    const float* __restrict__ bih_post, const float* __restrict__ bhh_post,
    const float* __restrict__ Wfc, const float* __restrict__ bfc,
    float* __restrict__ out, float* __restrict__ ws)
{
  float* buf0 = ws + OFF_BUF0;
  float* pctx = ws + OFF_PCTX;
  float* pml  = ws + OFF_PML;
  float* h3   = ws + OFF_H3;
  unsigned* gflags = (unsigned*)(ws + OFF_GFLAGS);

  const int wg   = blockIdx.x;
  const int tid  = threadIdx.x;
  const int lane = tid & 63;
  const int wv   = tid >> 6;
  const int b    = wg & 63;    // batch owned by this WG (4 WGs per batch)
  const int part = wg >> 6;    // 0..3: j-part for GEMVs, s-strip for 3a

  unsigned* bflags = (unsigned*)(ws + OFF_BFLAGS) + (size_t)b * 4 * 32;
  unsigned gen = 0;

  __shared__ float smem[8208];

  // ================= P1: x_proj = inputs @ W_ih_pre^T + (b_ih+b_hh) ==========
  {
    const int h = tid;
    float4 Wr[32];
    const float4* wrow = (const float4*)(Wih_pre + (size_t)h * I);
    #pragma unroll
    for (int c = 0; c < 32; ++c) Wr[c] = wrow[c];
    const float bias = bih_pre[h] + bhh_pre[h];
    const int r0 = wg * 128;
    for (int t2 = 0; t2 < 2; ++t2) {
      __syncthreads();
      const float4* src = (const float4*)(inputs + (size_t)(r0 + t2 * 64) * I);
      for (int idx = tid; idx < 64 * I / 4; idx += NTHR)
        ((float4*)smem)[idx] = src[idx];
      __syncthreads();
      for (int r = 0; r < 64; ++r) {
        const float4* arow = (const float4*)(smem + r * I);
        float acc0 = 0.f, acc1 = 0.f;
        #pragma unroll
        for (int c = 0; c < 32; c += 2) {
          float4 a0 = arow[c], a1 = arow[c + 1];
          acc0 += a0.x * Wr[c].x + a0.y * Wr[c].y + a0.z * Wr[c].z + a0.w * Wr[c].w;
          acc1 += a1.x * Wr[c+1].x + a1.y * Wr[c+1].y + a1.z * Wr[c+1].z + a1.w * Wr[c+1].w;
        }
        buf0[(size_t)(r0 + t2 * 64 + r) * H + h] = acc0 + acc1 + bias;
      }
    }
  }
  // ---- ONE-TIME 256-WG acq/rel barrier: flush P1's normal stores to L3 and
  //      invalidate local caches so P2's normal x_proj reads are fresh.
  __syncthreads();
  if (tid == 0)
    __hip_atomic_store(gflags + (size_t)wg * 32, 1u, __ATOMIC_RELEASE, __HIP_MEMORY_SCOPE_AGENT);
  if (tid < 256) {
    while (__hip_atomic_load(gflags + (size_t)tid * 32, __ATOMIC_ACQUIRE,
                             __HIP_MEMORY_SCOPE_AGENT) < 1u) {}
  }
  __syncthreads();

  // ================= P2: pre-RNN, 512 steps, per-batch (4 WGs) ==============
  // thread: j = part*128 + (tid>>2), k-quad kq = tid&3, k-blocks interleaved
  {
    const int j  = part * 128 + (tid >> 2);
    const int kq = tid & 3;
    float4 wpre[32];
    const float4* wrow = (const float4*)(Whh_pre + (size_t)j * H);
    #pragma unroll
    for (int i = 0; i < 32; ++i) wpre[i] = wrow[4 * i + kq];

    float* hst   = smem;            // [512] current h for this batch
    float4* hst4 = (float4*)smem;
    hst[tid] = 0.f;
    __syncthreads();

    for (int t = 0; t < S; ++t) {
      float* brow = buf0 + ((size_t)t * B + b) * H;
      float xp = brow[j];  // x_proj (normal cached load), incl. both biases
      float d = 0.f;
      #pragma unroll
      for (int i = 0; i < 32; ++i) {
        float4 hv = hst4[4 * i + kq];
        d += wpre[i].x * hv.x + wpre[i].y * hv.y + wpre[i].z * hv.z + wpre[i].w * hv.w;
      }
      d += __shfl_xor(d, 1);
      d += __shfl_xor(d, 2);
      float hnew = tanhf(xp + d);
      if (kq == 0) cstore(brow + j, hnew);   // coherent: other parts read it
      bar4(bflags, part, ++gen);
      hst[tid] = cload(brow + tid);          // reload full h_t (coherent)
      __syncthreads();
    }
  }

  // ---- G = out_pre strip (128 s-rows), register-resident ----
  // sc1 loads: own L1/L2 hold stale x_proj copies of these lines.
  float4 ga[16], gb[16];
  {
    const int s0 = part * 128 + wv * 16;
    #pragma unroll
    for (int i = 0; i < 16; ++i) {
      const float* row = buf0 + ((size_t)(s0 + i) * B + b) * H;
      float2 q0 = cload2(row + lane * 4),       q1 = cload2(row + lane * 4 + 2);
      float2 q2 = cload2(row + 256 + lane * 4), q3 = cload2(row + 256 + lane * 4 + 2);
      ga[i] = float4{q0.x, q0.y, q1.x, q1.y};
      gb[i] = float4{q2.x, q2.y, q3.x, q3.y};
    }
  }

  // ---- 3c stationary weights: [W_ih_post | W_hh_post] ----
  const int j3 = part * 128 + (tid >> 2);
  const int kq = tid & 3;
  float4 wih[32], whh[32];
  {
    const float4* wr1 = (const float4*)(Wih_post + (size_t)j3 * H);
    const float4* wr2 = (const float4*)(Whh_post + (size_t)j3 * H);
    #pragma unroll
    for (int i = 0; i < 32; ++i) { wih[i] = wr1[4 * i + kq]; whh[i] = wr2[4 * i + kq]; }
  }
  const float bp3 = bih_post[j3] + bhh_post[j3];

  // ================= P3: attention loop, 512 steps, per-batch ================
  for (int u = 0; u < H; ++u) {
    const float* hin = h3 + (size_t)(u & 1) * (B * H) + (size_t)b * H;
    float* hout      = h3 + (size_t)((u + 1) & 1) * (B * H) + (size_t)b * H;

    // ---- 3a: scores + softmax partials + ctx partial (registers) ----
    {
      float2 q0 = cload2(hin + lane * 4),       q1 = cload2(hin + lane * 4 + 2);
      float2 q2 = cload2(hin + 256 + lane * 4), q3 = cload2(hin + 256 + lane * 4 + 2);
      float4 h0v{q0.x, q0.y, q1.x, q1.y};
      float4 h1v{q2.x, q2.y, q3.x, q3.y};
      float p[16];
      #pragma unroll
      for (int i = 0; i < 16; ++i)
        p[i] = ga[i].x * h0v.x + ga[i].y * h0v.y + ga[i].z * h0v.z + ga[i].w * h0v.w
             + gb[i].x * h1v.x + gb[i].y * h1v.y + gb[i].z * h1v.z + gb[i].w * h1v.w;
      #pragma unroll
      for (int off = 32; off > 0; off >>= 1) {
        #pragma unroll
        for (int i = 0; i < 16; ++i) p[i] += __shfl_xor(p[i], off);
      }
      float m = p[0];
      #pragma unroll
      for (int i = 1; i < 16; ++i) m = fmaxf(m, p[i]);
      float l = 0.f;
      float4 c0{0.f,0.f,0.f,0.f}, c1{0.f,0.f,0.f,0.f};
      #pragma unroll
      for (int i = 0; i < 16; ++i) {
        float e = __expf(p[i] - m);
        l += e;
        c0.x += e * ga[i].x;  c0.y += e * ga[i].y;  c0.z += e * ga[i].z;  c0.w += e * ga[i].w;
        c1.x += e * gb[i].x;  c1.y += e * gb[i].y;  c1.z += e * gb[i].z;  c1.w += e * gb[i].w;
      }
      float* ctx_lds = smem;          // [8][512]
      float* ml_lds  = smem + 4096;   // [8][2]
      *(float4*)(ctx_lds + wv * 512 + lane * 4)       = c0;
      *(float4*)(ctx_lds + wv * 512 + 256 + lane * 4) = c1;
      if (lane == 0) { ml_lds[wv * 2] = m; ml_lds[wv * 2 + 1] = l; }
      __syncthreads();
      float mstar = ml_lds[0];
      #pragma unroll
      for (int w = 1; w < 8; ++w) mstar = fmaxf(mstar, ml_lds[w * 2]);
      float lsum = 0.f, csum = 0.f;
      #pragma unroll
      for (int w = 0; w < 8; ++w) {
        float sc = __expf(ml_lds[w * 2] - mstar);
        lsum += sc * ml_lds[w * 2 + 1];
        csum += sc * ctx_lds[w * 512 + tid];
      }
      cstore(pctx + ((size_t)b * 4 + part) * H + tid, csum);
      if (tid == 0) {
        cstore(pml + ((size_t)b * 4 + part) * 2,     mstar);
        cstore(pml + ((size_t)b * 4 + part) * 2 + 1, lsum);
      }
    }
    bar4(bflags, part, ++gen);

    // ---- 3c: merge 4 strip partials -> ctx; h-update GEMV (stationary W) ----
    {
      float* ctx2 = smem;          // [512]
      float* hst  = smem + 512;    // [512]
      const float* ml8 = pml + (size_t)b * 8;
      float m0 = cload(ml8 + 0), l0 = cload(ml8 + 1), m1 = cload(ml8 + 2), l1 = cload(ml8 + 3);
      float m2 = cload(ml8 + 4), l2 = cload(ml8 + 5), m3 = cload(ml8 + 6), l3 = cload(ml8 + 7);
      float mb = fmaxf(fmaxf(m0, m1), fmaxf(m2, m3));
      float s0 = __expf(m0 - mb), s1 = __expf(m1 - mb);
      float s2 = __expf(m2 - mb), s3 = __expf(m3 - mb);
      float inv = 1.0f / (s0 * l0 + s1 * l1 + s2 * l2 + s3 * l3);
      const float* pc = pctx + (size_t)b * 4 * H;
      ctx2[tid] = (s0 * cload(pc + tid) + s1 * cload(pc + H + tid) +
                   s2 * cload(pc + 2 * H + tid) + s3 * cload(pc + 3 * H + tid)) * inv;
      hst[tid] = cload(hin + tid);
      __syncthreads();
      const float4* ctx4 = (const float4*)ctx2;
      const float4* hh4  = (const float4*)hst;
      float acc = 0.f;
      #pragma unroll
      for (int i = 0; i < 32; ++i) {
        float4 cv = ctx4[4 * i + kq];
        float4 hv = hh4[4 * i + kq];
        acc += wih[i].x * cv.x + wih[i].y * cv.y + wih[i].z * cv.z + wih[i].w * cv.w
             + whh[i].x * hv.x + whh[i].y * hv.y + whh[i].z * hv.z + whh[i].w * hv.w;
      }
      acc += __shfl_xor(acc, 1);
      acc += __shfl_xor(acc, 2);
      if (kq == 0) cstore(hout + j3, tanhf(acc + bp3));
    }
    bar4(bflags, part, ++gen);
  }

  // ================= final: out = h_post @ W_fc^T + b_fc =====================
  if (part == 0) {
    const float* hf = h3 + (size_t)b * H;   // 512 steps -> parity slot 0
    float pv = cload(hf + tid) * Wfc[tid];
    #pragma unroll
    for (int off = 32; off > 0; off >>= 1) pv += __shfl_xor(pv, off);
    __syncthreads();
    if (lane == 0) smem[wv] = pv;
    __syncthreads();
    if (tid == 0) {
      float s = 0.f;
      #pragma unroll
      for (int w = 0; w < 8; ++w) s += smem[w];
      out[b] = s + bfc[0];
    }
  }
}

extern "C" void kernel_launch(void* const* d_in, const int* in_sizes, int n_in,
                              void* d_out, int out_size, void* d_ws, size_t ws_size,
                              hipStream_t stream) {
  (void)in_sizes; (void)n_in; (void)out_size; (void)ws_size;
  const float* inputs   = (const float*)d_in[0];
  const float* Wih_pre  = (const float*)d_in[1];
  const float* Whh_pre  = (const float*)d_in[2];
  const float* bih_pre  = (const float*)d_in[3];
  const float* bhh_pre  = (const float*)d_in[4];
  const float* Wih_post = (const float*)d_in[5];
  const float* Whh_post = (const float*)d_in[6];
  const float* bih_post = (const float*)d_in[7];
  const float* bhh_post = (const float*)d_in[8];
  const float* Wfc      = (const float*)d_in[9];
  const float* bfc      = (const float*)d_in[10];
  float* out = (float*)d_out;
  float* ws  = (float*)d_ws;

  // Zero h3 ping-pong + all barrier flags (contiguous region), every launch.
  hipMemsetAsync((char*)d_ws + OFF_H3 * sizeof(float), 0,
                 (OFF_END - OFF_H3) * sizeof(float), stream);

  attn_fused<<<dim3(NWG), dim3(NTHR), 0, stream>>>(
      inputs, Wih_pre, Whh_pre, bih_pre, bhh_pre,
      Wih_post, Whh_post, bih_post, bhh_post, Wfc, bfc, out, ws);
}

// Round 5
// 14229.826 us; speedup vs baseline: 3.6558x; 1.1472x over previous
//
#include <hip/hip_runtime.h>
#include <math.h>

#define NWG 256
#define NTHR 512
static constexpr int S = 512, B = 64, I = 128, H = 512;

// ws layout (float units)
static constexpr size_t OFF_BUF0   = 0;                                  // S*B*H: x_proj -> out_pre in place
static constexpr size_t OFF_PCTX   = (size_t)S * B * H;                  // [64][4][520] pctx blocks (P2 h-exch unions here)
static constexpr size_t OFF_H3X    = OFF_PCTX + (size_t)64 * 4 * 520;    // [64][4][128] P3 h quarters
static constexpr size_t OFF_ACTR   = OFF_H3X + (size_t)64 * 4 * 128;     // [64][4][16] u32 pctx counters
static constexpr size_t OFF_HCTR   = OFF_ACTR + (size_t)64 * 4 * 16;     // [64][4][16] u32 h counters (P2: 1..512, P3: 513..1024)
static constexpr size_t OFF_GFLAGS = OFF_HCTR + (size_t)64 * 4 * 16;     // [256][16] u32 global barrier flags
static constexpr size_t OFF_END    = OFF_GFLAGS + (size_t)256 * 16;
// total = 67,821,568 bytes  (< proven ws floor of 68,225,024)

typedef float f32x2 __attribute__((ext_vector_type(2)));
typedef float f32x4 __attribute__((ext_vector_type(4)));

// ---- coherent (sc0 sc1: L1+L2 bypass, served at L3 coherence point) ops ----
__device__ __forceinline__ void st_g1(float* p, float v) {
  asm volatile("global_store_dword %0, %1, off sc0 sc1" :: "v"(p), "v"(v) : "memory");
}
__device__ __forceinline__ void st_g2(float* p, f32x2 v) {
  asm volatile("global_store_dwordx2 %0, %1, off sc0 sc1" :: "v"(p), "v"(v) : "memory");
}
__device__ __forceinline__ void st_gu(unsigned* p, unsigned v) {
  asm volatile("global_store_dword %0, %1, off sc0 sc1" :: "v"(p), "v"(v) : "memory");
}
__device__ __forceinline__ f32x4 ld_g4(const float* p) {
  f32x4 v;
  asm volatile("global_load_dwordx4 %0, %1, off sc0 sc1\n\ts_waitcnt vmcnt(0)"
               : "=&v"(v) : "v"(p) : "memory");
  return v;
}
// 3 peer pctx values + 3 peer (m,l) pairs, one batched round trip
__device__ __forceinline__ void ld_3c(const float* v0, const float* v1, const float* v2,
                                      const float* m0, const float* m1, const float* m2,
                                      float& a, float& b, float& c,
                                      f32x2& x, f32x2& y, f32x2& z) {
  asm volatile("global_load_dword %0, %6, off sc0 sc1\n\t"
               "global_load_dword %1, %7, off sc0 sc1\n\t"
               "global_load_dword %2, %8, off sc0 sc1\n\t"
               "global_load_dwordx2 %3, %9, off sc0 sc1\n\t"
               "global_load_dwordx2 %4, %10, off sc0 sc1\n\t"
               "global_load_dwordx2 %5, %11, off sc0 sc1\n\t"
               "s_waitcnt vmcnt(0)"
               : "=&v"(a), "=&v"(b), "=&v"(c), "=&v"(x), "=&v"(y), "=&v"(z)
               : "v"(v0), "v"(v1), "v"(v2), "v"(m0), "v"(m1), "v"(m2) : "memory");
}
__device__ __forceinline__ void poll3_ge(const unsigned* p0, const unsigned* p1,
                                         const unsigned* p2, unsigned tgt) {
  unsigned a, b, c;
  do {
    asm volatile("global_load_dword %0, %3, off sc0 sc1\n\t"
                 "global_load_dword %1, %4, off sc0 sc1\n\t"
                 "global_load_dword %2, %5, off sc0 sc1\n\t"
                 "s_waitcnt vmcnt(0)"
                 : "=&v"(a), "=&v"(b), "=&v"(c)
                 : "v"(p0), "v"(p1), "v"(p2) : "memory");
  } while (a < tgt || b < tgt || c < tgt);
}
__device__ __forceinline__ void vm_drain() { asm volatile("s_waitcnt vmcnt(0)" ::: "memory"); }

// one-time global barrier, acq/rel (flush dirty L2 / invalidate local caches)
__device__ __forceinline__ void gbar_all(unsigned* gflags, int wg, unsigned gen) {
  __syncthreads();
  if (threadIdx.x == 0)
    __hip_atomic_store(gflags + (size_t)wg * 16, gen, __ATOMIC_RELEASE, __HIP_MEMORY_SCOPE_AGENT);
  if (threadIdx.x < 256) {
    while (__hip_atomic_load(gflags + (size_t)threadIdx.x * 16, __ATOMIC_ACQUIRE,
                             __HIP_MEMORY_SCOPE_AGENT) < gen) {}
  }
  __syncthreads();
}

__global__ __launch_bounds__(NTHR, 2) void attn_fused(
    const float* __restrict__ inputs,
    const float* __restrict__ Wih_pre, const float* __restrict__ Whh_pre,
    const float* __restrict__ bih_pre, const float* __restrict__ bhh_pre,
    const float* __restrict__ Wih_post, const float* __restrict__ Whh_post,
    const float* __restrict__ bih_post, const float* __restrict__ bhh_post,
    const float* __restrict__ Wfc, const float* __restrict__ bfc,
    float* __restrict__ out, float* __restrict__ ws)
{
  float* buf0  = ws + OFF_BUF0;
  float* pctxg = ws + OFF_PCTX;
  float* h3xg  = ws + OFF_H3X;
  unsigned* actrg  = (unsigned*)(ws + OFF_ACTR);
  unsigned* hctrg  = (unsigned*)(ws + OFF_HCTR);
  unsigned* gflags = (unsigned*)(ws + OFF_GFLAGS);

  const int wg   = blockIdx.x;
  const int tid  = threadIdx.x;
  const int lane = tid & 63;
  const int wv   = tid >> 6;
  const int b    = wg & 63;    // batch owned by this WG (4 WGs per batch)
  const int part = wg >> 6;    // 0..3: j-part for GEMVs, s-strip for 3a
  const int q1 = (part + 1) & 3, q2 = (part + 2) & 3, q3 = (part + 3) & 3;

  unsigned* hc_own = hctrg + ((size_t)b * 4 + part) * 16;
  unsigned* hc1 = hctrg + ((size_t)b * 4 + q1) * 16;
  unsigned* hc2 = hctrg + ((size_t)b * 4 + q2) * 16;
  unsigned* hc3 = hctrg + ((size_t)b * 4 + q3) * 16;
  unsigned* ac_own = actrg + ((size_t)b * 4 + part) * 16;
  unsigned* ac1 = actrg + ((size_t)b * 4 + q1) * 16;
  unsigned* ac2 = actrg + ((size_t)b * 4 + q2) * 16;
  unsigned* ac3 = actrg + ((size_t)b * 4 + q3) * 16;

  // smem map: [0,512) hst (current h) | [512,1024) own_pctx | [1024,5120) merge/ctx2 | [5120,5136) ml
  // P1 uses [0,8192) as input tile.
  __shared__ float smem[8208];

  // ================= P1: x_proj = inputs @ W_ih_pre^T + (b_ih+b_hh) ==========
  {
    const int h = tid;
    float4 Wr[32];
    const float4* wrow = (const float4*)(Wih_pre + (size_t)h * I);
    #pragma unroll
    for (int c = 0; c < 32; ++c) Wr[c] = wrow[c];
    const float bias = bih_pre[h] + bhh_pre[h];
    const int r0 = wg * 128;
    for (int t2 = 0; t2 < 2; ++t2) {
      __syncthreads();
      const float4* src = (const float4*)(inputs + (size_t)(r0 + t2 * 64) * I);
      for (int idx = tid; idx < 64 * I / 4; idx += NTHR)
        ((float4*)smem)[idx] = src[idx];
      __syncthreads();
      for (int r = 0; r < 64; ++r) {
        const float4* arow = (const float4*)(smem + r * I);
        float acc0 = 0.f, acc1 = 0.f;
        #pragma unroll
        for (int c = 0; c < 32; c += 2) {
          float4 a0 = arow[c], a1 = arow[c + 1];
          acc0 += a0.x * Wr[c].x + a0.y * Wr[c].y + a0.z * Wr[c].z + a0.w * Wr[c].w;
          acc1 += a1.x * Wr[c+1].x + a1.y * Wr[c+1].y + a1.z * Wr[c+1].z + a1.w * Wr[c+1].w;
        }
        buf0[(size_t)(r0 + t2 * 64 + r) * H + h] = acc0 + acc1 + bias;
      }
    }
  }
  gbar_all(gflags, wg, 1u);   // flush x_proj to coherence point

  // ================= P2: pre-RNN, 512 steps, per-batch (4 WGs) ==============
  const int j  = part * 128 + (tid >> 2);
  const int kq = tid & 3;
  {
    float4 wpre[32];
    const float4* wrow = (const float4*)(Whh_pre + (size_t)j * H);
    #pragma unroll
    for (int i = 0; i < 32; ++i) wpre[i] = wrow[4 * i + kq];

    smem[tid] = 0.f;   // h_0 = 0
    __syncthreads();

    for (int t = 0; t < S; ++t) {
      float* brow = buf0 + ((size_t)t * B + b) * H;
      float xp = brow[j];  // normal cached load (incl. both biases)
      const float4* hst4 = (const float4*)smem;
      float d = 0.f;
      #pragma unroll
      for (int i = 0; i < 32; ++i) {
        float4 hv = hst4[4 * i + kq];   // broadcast, conflict-free
        d += wpre[i].x * hv.x + wpre[i].y * hv.y + wpre[i].z * hv.z + wpre[i].w * hv.w;
      }
      d += __shfl_xor(d, 1);
      d += __shfl_xor(d, 2);
      float hnew = tanhf(xp + d);
      const int par = (t + 1) & 1;
      float* slot = pctxg + (((size_t)b * 2 + par) * 4 + part) * 128;  // P2 h-exch (unions pctx region)
      if (kq == 0) {
        brow[j] = hnew;                 // out_pre, normal store (read after global barrier)
        st_g1(slot + (tid >> 2), hnew); // coherent exchange copy
      }
      vm_drain();
      __syncthreads();
      if (tid == 0) st_gu(hc_own, (unsigned)(t + 1));
      poll3_ge(hc1, hc2, hc3, (unsigned)(t + 1));
      if (tid < 128) {
        f32x4 hv = ld_g4(pctxg + (((size_t)b * 2 + par) * 4) * 128 + (size_t)tid * 4);
        ((float4*)smem)[tid] = float4{hv.x, hv.y, hv.z, hv.w};
      }
      __syncthreads();
    }
  }
  gbar_all(gflags, wg, 2u);   // flush out_pre; invalidate local caches

  // ---- G = out_pre strip (128 s-rows), register-resident (normal loads) ----
  float4 ga[16], gb[16];
  {
    const int s0 = part * 128 + wv * 16;
    #pragma unroll
    for (int i = 0; i < 16; ++i) {
      const float* row = buf0 + ((size_t)(s0 + i) * B + b) * H;
      ga[i] = *(const float4*)(row + lane * 4);
      gb[i] = *(const float4*)(row + 256 + lane * 4);
    }
  }

  // ---- 3c stationary weights ----
  float4 wih[32], whh[32];
  {
    const float4* wr1 = (const float4*)(Wih_post + (size_t)j * H);
    const float4* wr2 = (const float4*)(Whh_post + (size_t)j * H);
    #pragma unroll
    for (int i = 0; i < 32; ++i) { wih[i] = wr1[4 * i + kq]; whh[i] = wr2[4 * i + kq]; }
  }
  const float bp3 = bih_post[j] + bhh_post[j];

  float* blk_own = pctxg + ((size_t)b * 4 + part) * 520;
  float* blk1 = pctxg + ((size_t)b * 4 + q1) * 520;
  float* blk2 = pctxg + ((size_t)b * 4 + q2) * 520;
  float* blk3 = pctxg + ((size_t)b * 4 + q3) * 520;

  smem[tid] = 0.f;   // attention h_0 = 0
  __syncthreads();

  // ================= P3: attention loop, 512 steps, per-batch ================
  for (int u = 0; u < H; ++u) {
    // ---- 3a: scores + softmax partials + ctx partial (registers + LDS h) ----
    float mstar, lsum;
    {
      float4 h0v = ((const float4*)smem)[lane];
      float4 h1v = ((const float4*)smem)[64 + lane];
      float p[16];
      #pragma unroll
      for (int i = 0; i < 16; ++i)
        p[i] = ga[i].x * h0v.x + ga[i].y * h0v.y + ga[i].z * h0v.z + ga[i].w * h0v.w
             + gb[i].x * h1v.x + gb[i].y * h1v.y + gb[i].z * h1v.z + gb[i].w * h1v.w;
      #pragma unroll
      for (int off = 32; off > 0; off >>= 1) {
        #pragma unroll
        for (int i = 0; i < 16; ++i) p[i] += __shfl_xor(p[i], off);
      }
      float m = p[0];
      #pragma unroll
      for (int i = 1; i < 16; ++i) m = fmaxf(m, p[i]);
      float l = 0.f;
      float4 c0{0.f,0.f,0.f,0.f}, c1{0.f,0.f,0.f,0.f};
      #pragma unroll
      for (int i = 0; i < 16; ++i) {
        float e = __expf(p[i] - m);
        l += e;
        c0.x += e * ga[i].x;  c0.y += e * ga[i].y;  c0.z += e * ga[i].z;  c0.w += e * ga[i].w;
        c1.x += e * gb[i].x;  c1.y += e * gb[i].y;  c1.z += e * gb[i].z;  c1.w += e * gb[i].w;
      }
      float* ctx_lds = smem + 1024;   // [8][512]
      float* ml_lds  = smem + 5120;   // [8][2]
      *(float4*)(ctx_lds + wv * 512 + lane * 4)       = c0;
      *(float4*)(ctx_lds + wv * 512 + 256 + lane * 4) = c1;
      if (lane == 0) { ml_lds[wv * 2] = m; ml_lds[wv * 2 + 1] = l; }
      __syncthreads();
      mstar = ml_lds[0];
      #pragma unroll
      for (int w = 1; w < 8; ++w) mstar = fmaxf(mstar, ml_lds[w * 2]);
      lsum = 0.f;
      float csum = 0.f;
      #pragma unroll
      for (int w = 0; w < 8; ++w) {
        float sc = __expf(ml_lds[w * 2] - mstar);
        lsum += sc * ml_lds[w * 2 + 1];
        csum += sc * ctx_lds[w * 512 + tid];
      }
      smem[512 + tid] = csum;                 // own pctx (LDS)
      st_g1(blk_own + tid, csum);             // publish payload
      if (tid == 0) st_g2(blk_own + 512, f32x2{mstar, lsum});
      vm_drain();
      __syncthreads();
      if (tid == 0) st_gu(ac_own, (unsigned)(u + 1));
    }

    // ---- 3c: merge 4 partials -> ctx; h-update GEMV (stationary W) ----
    {
      poll3_ge(ac1, ac2, ac3, (unsigned)(u + 1));
      float v1, v2, v3; f32x2 mlA, mlB, mlC;
      ld_3c(blk1 + tid, blk2 + tid, blk3 + tid,
            blk1 + 512, blk2 + 512, blk3 + 512, v1, v2, v3, mlA, mlB, mlC);
      float mb = fmaxf(fmaxf(mstar, mlA.x), fmaxf(mlB.x, mlC.x));
      float s0 = __expf(mstar - mb), s1 = __expf(mlA.x - mb);
      float s2 = __expf(mlB.x - mb), s3 = __expf(mlC.x - mb);
      float inv = 1.0f / (s0 * lsum + s1 * mlA.y + s2 * mlB.y + s3 * mlC.y);
      float cval = (s0 * smem[512 + tid] + s1 * v1 + s2 * v2 + s3 * v3) * inv;
      smem[1024 + tid] = cval;   // ctx2
      __syncthreads();
      const float4* ctx4 = (const float4*)(smem + 1024);
      const float4* hh4  = (const float4*)smem;
      float acc = 0.f;
      #pragma unroll
      for (int i = 0; i < 32; ++i) {
        float4 cv = ctx4[4 * i + kq];
        float4 hv = hh4[4 * i + kq];
        acc += wih[i].x * cv.x + wih[i].y * cv.y + wih[i].z * cv.z + wih[i].w * cv.w
             + whh[i].x * hv.x + whh[i].y * hv.y + whh[i].z * hv.z + whh[i].w * hv.w;
      }
      acc += __shfl_xor(acc, 1);
      acc += __shfl_xor(acc, 2);
      float hnew = tanhf(acc + bp3);
      if (kq == 0) st_g1(h3xg + ((size_t)b * 4 + part) * 128 + (tid >> 2), hnew);
      vm_drain();
      __syncthreads();
      if (tid == 0) st_gu(hc_own, (unsigned)(513 + u));
      poll3_ge(hc1, hc2, hc3, (unsigned)(513 + u));
      if (tid < 128) {
        f32x4 hv = ld_g4(h3xg + (size_t)b * 4 * 128 + (size_t)tid * 4);
        ((float4*)smem)[tid] = float4{hv.x, hv.y, hv.z, hv.w};
      }
      __syncthreads();
    }
  }

  // ================= final: out = h_post @ W_fc^T + b_fc =====================
  if (part == 0) {
    float pv = smem[tid] * Wfc[tid];
    #pragma unroll
    for (int off = 32; off > 0; off >>= 1) pv += __shfl_xor(pv, off);
    __syncthreads();
    if (lane == 0) smem[5120 + wv] = pv;
    __syncthreads();
    if (tid == 0) {
      float s = 0.f;
      #pragma unroll
      for (int w = 0; w < 8; ++w) s += smem[5120 + w];
      out[b] = s + bfc[0];
    }
  }
}

extern "C" void kernel_launch(void* const* d_in, const int* in_sizes, int n_in,
                              void* d_out, int out_size, void* d_ws, size_t ws_size,
                              hipStream_t stream) {
  (void)in_sizes; (void)n_in; (void)out_size; (void)ws_size;
  const float* inputs   = (const float*)d_in[0];
  const float* Wih_pre  = (const float*)d_in[1];
  const float* Whh_pre  = (const float*)d_in[2];
  const float* bih_pre  = (const float*)d_in[3];
  const float* bhh_pre  = (const float*)d_in[4];
  const float* Wih_post = (const float*)d_in[5];
  const float* Whh_post = (const float*)d_in[6];
  const float* bih_post = (const float*)d_in[7];
  const float* bhh_post = (const float*)d_in[8];
  const float* Wfc      = (const float*)d_in[9];
  const float* bfc      = (const float*)d_in[10];
  float* out = (float*)d_out;
  float* ws  = (float*)d_ws;

  // Zero all counters + global barrier flags every launch (graph-replay safe).
  hipMemsetAsync((char*)d_ws + OFF_ACTR * sizeof(float), 0,
                 (OFF_END - OFF_ACTR) * sizeof(float), stream);

  attn_fused<<<dim3(NWG), dim3(NTHR), 0, stream>>>(
      inputs, Wih_pre, Whh_pre, bih_pre, bhh_pre,
      Wih_post, Whh_post, bih_post, bhh_post, Wfc, bfc, out, ws);
}